// Round 4
// baseline (298.468 us; speedup 1.0000x reference)
//
#include <hip/hip_runtime.h>
#include <math.h>

#define NB   128
#define CF   1024
#define RR   256
#define NA   312
#define DV   300
#define MT   640
#define NKC  32
#define NQ   160

typedef _Float16 half8  __attribute__((ext_vector_type(8)));
typedef _Float16 half4  __attribute__((ext_vector_type(4)));
typedef float float16v  __attribute__((ext_vector_type(16)));
typedef float float4v   __attribute__((ext_vector_type(4)));

// async global->LDS, 16B per lane; LDS dest = wave-uniform base + lane*16.
__device__ __forceinline__ void gll16(const void* g, void* l) {
    __builtin_amdgcn_global_load_lds(
        (const __attribute__((address_space(1))) void*)g,
        (__attribute__((address_space(3))) void*)l, 16, 0, 0);
}

// ---- K1: prep via DMA staging. One block per (b,kc); thread t = column r. ----
__launch_bounds__(256, 4)
__global__ void k_prep(const float* __restrict__ img, float* __restrict__ ssq32,
                       _Float16* __restrict__ avT) {
    int m  = blockIdx.x;
    int kc = m & 31;
    int b  = m >> 5;
    int t  = threadIdx.x;
    __shared__ __align__(16) float tile[32][256];   // 32 KB, mirrors global layout

    // contiguous 32 KB global span -> linear LDS, 8 x 16B DMA per thread
    const char* src = (const char*)(img + ((size_t)b * CF + kc * 32) * RR);
    #pragma unroll
    for (int i = 0; i < 8; ++i)
        gll16(src + (size_t)i * 4096 + (size_t)t * 16,
              (char*)tile + i * 4096 + t * 16);
    asm volatile("s_waitcnt vmcnt(0)" ::: "memory");
    __syncthreads();

    // thread t owns r = t: read 32 f values (bank = t%32, conflict-free)
    float v[32];
    #pragma unroll
    for (int f = 0; f < 32; ++f) v[f] = tile[f][t];
    float ss = 0.f;
    #pragma unroll
    for (int f = 0; f < 32; ++f) ss += v[f] * v[f];

    // dense 64-B row store: avT[(b,kc)][r=t][0..31 f]
    _Float16* dst = avT + ((size_t)(b * NKC + kc) * RR + t) * 32;
    #pragma unroll
    for (int s = 0; s < 4; ++s) {
        half8 o;
        #pragma unroll
        for (int j = 0; j < 8; ++j) o[j] = (_Float16)v[s * 8 + j];
        *(half8*)(dst + s * 8) = o;
    }
    ssq32[(size_t)(b * NKC + kc) * RR + t] = ss;
}

// ---- K1b: Q projection (pair-interleaved Qb rows), standalone ----
__launch_bounds__(256, 4)
__global__ void k_q(const float* __restrict__ V, const float* __restrict__ W1,
                    const float* __restrict__ W2, _Float16* __restrict__ Qb) {
    int ib = blockIdx.x;
    int t  = threadIdx.x;
    bool isQ2 = ib >= 80;
    int i0l = (ib - (isQ2 ? 80 : 0)) * 4;     // pair base 0..316
    __shared__ float inv4[4];
    float acc[4][4];
    #pragma unroll
    for (int ii = 0; ii < 4; ++ii)
        #pragma unroll
        for (int j = 0; j < 4; ++j) acc[ii][j] = 0.f;
    if (i0l < NA) {
        int row = t >> 6, l64 = t & 63;
        float s = 0.f;
        for (int v = l64; v < DV; v += 64) { float x = V[(i0l + row) * DV + v]; s += x * x; }
        #pragma unroll
        for (int o = 32; o; o >>= 1) s += __shfl_xor(s, o, 64);
        if (l64 == 0) inv4[row] = 1.f / fmaxf(sqrtf(s), 1e-12f);
        __syncthreads();
        const float* W  = isQ2 ? W2 : W1;
        const float* Vb = V + (size_t)i0l * DV;
        for (int v = 0; v < DV; v += 2) {
            float4v w0 = *(const float4v*)(W + (size_t)v * CF + t * 4);
            float4v w1 = *(const float4v*)(W + (size_t)(v + 1) * CF + t * 4);
            #pragma unroll
            for (int ii = 0; ii < 4; ++ii) {
                float a0 = Vb[(size_t)ii * DV + v];
                float a1 = Vb[(size_t)ii * DV + v + 1];
                #pragma unroll
                for (int j = 0; j < 4; ++j) acc[ii][j] += a0 * w0[j] + a1 * w1[j];
            }
        }
        #pragma unroll
        for (int ii = 0; ii < 4; ++ii)
            #pragma unroll
            for (int j = 0; j < 4; ++j) acc[ii][j] *= inv4[ii];
    }
    int fg = t >> 3;
    int fo = (t & 7) * 4;
    int q12 = isQ2 ? 1 : 0;
    #pragma unroll
    for (int ii = 0; ii < 4; ++ii) {
        half4 h;
        #pragma unroll
        for (int j = 0; j < 4; ++j) h[j] = (_Float16)acc[ii][j];
        *(half4*)&Qb[((size_t)fg * MT + (2 * (i0l + ii) + q12)) * 32 + fo] = h;
    }
}

// ---- K2: one block per (b, half): M=320 x N=256, 8 waves, 3-buf pipeline ----
extern __shared__ char smem[];
__launch_bounds__(512, 2)
__global__ void k_gemm(const _Float16* __restrict__ Qb, const _Float16* __restrict__ avT,
                       const float* __restrict__ ssq32, float* __restrict__ out) {
    int lin = blockIdx.x;              // 0..255
    int xcd = lin & 7;
    int u   = lin >> 3;                // 0..31
    int b   = xcd + 8 * (u & 15);      // both halves of b share an XCD
    int t2h = u >> 4;                  // 0/1: pair range [t2h*160, +160)

    int tid  = threadIdx.x;
    int lane = tid & 63;
    int w    = tid >> 6;               // 0..7
    int wm   = w >> 2;                 // 0..1  (M split: 160 rows each)
    int wn   = w & 3;                  // 0..3  (N split: 64 cols each)
    int nl   = lane & 31;
    int kh   = lane >> 5;

    // chunk-linear staging addresses (A: [kb4][320 rows][16B], B: [kb4][256 rows][16B])
    int c1 = 512 + tid;
    int a_s0 = (tid % 320) * 64 + (tid / 320) * 16;
    int a_s1 = (c1 % 320) * 64 + (c1 / 320) * 16;
    int a_s2 = ((tid & 255) + 64) * 64 + 3 * 16;        // c2 = 1024 + (tid&255)
    int a_d0 = tid * 16;
    int a_d1 = a_d0 + 8192;
    int a_d2 = 16384 + (tid & 255) * 16;                // waves 4-7 duplicate (same data)
    int b_s0 = (tid & 255) * 64 + (tid >> 8) * 16;

    const char* Abase_g = (const char*)Qb;
    const char* Bbase_g = (const char*)avT + ((size_t)b * NKC) * RR * 64;

    float16v acc[5][2];
    #pragma unroll
    for (int i = 0; i < 5; ++i)
        #pragma unroll
        for (int j = 0; j < 2; ++j)
            #pragma unroll
            for (int gi = 0; gi < 16; ++gi) acc[i][j][gi] = 0.f;

    char* p0 = smem;                 // read buffer (kc % 3)
    char* p1 = smem + 36864;
    char* p2 = smem + 73728;         // stage target (kc+2)

    #define STAGE(kc_, buf) do {                                                   \
        int kcl = (kc_) < NKC ? (kc_) : (NKC - 1);                                 \
        const char* aS = Abase_g + ((size_t)kcl * MT + (size_t)t2h * 320) * 64;    \
        const char* bS = Bbase_g + (size_t)kcl * RR * 64;                          \
        char* ab = (buf); char* bb = (buf) + 20480;                                \
        gll16(aS + a_s0, ab + a_d0);                                               \
        gll16(aS + a_s1, ab + a_d1);                                               \
        gll16(aS + a_s2, ab + a_d2);                                               \
        gll16(bS + b_s0,      bb + tid * 16);                                      \
        gll16(bS + b_s0 + 32, bb + tid * 16 + 8192);                               \
    } while (0)

    #define COMPUTE(buf) do {                                                      \
        const char* Al = (buf); const char* Bl = (buf) + 20480;                    \
        _Pragma("unroll")                                                          \
        for (int ks = 0; ks < 2; ++ks) {                                           \
            int kb = ks * 2 + kh;                                                  \
            half8 bf0 = *(const half8*)(Bl + ((size_t)kb * 256 + wn * 64 + nl) * 16);      \
            half8 bf1 = *(const half8*)(Bl + ((size_t)kb * 256 + wn * 64 + 32 + nl) * 16); \
            _Pragma("unroll")                                                      \
            for (int mt = 0; mt < 5; ++mt) {                                       \
                half8 af = *(const half8*)(Al + ((size_t)kb * 320 + wm * 160 + mt * 32 + nl) * 16); \
                acc[mt][0] = __builtin_amdgcn_mfma_f32_32x32x16_f16(af, bf0, acc[mt][0], 0, 0, 0);  \
                acc[mt][1] = __builtin_amdgcn_mfma_f32_32x32x16_f16(af, bf1, acc[mt][1], 0, 0, 0);  \
            }                                                                      \
        }                                                                          \
    } while (0)

    STAGE(0, p0);
    __builtin_amdgcn_sched_barrier(0);
    STAGE(1, p1);
    asm volatile("s_waitcnt vmcnt(5)" ::: "memory");   // stage(0) landed (mine)
    __builtin_amdgcn_s_barrier();                      // stage(0) landed (all)
    __builtin_amdgcn_sched_barrier(0);

    #pragma unroll 1
    for (int kc = 0; kc < NKC; ++kc) {
        STAGE(kc + 2, p2);                             // overwrites buf read at kc-1 (safe: post-barrier)
        asm volatile("s_waitcnt vmcnt(5)" ::: "memory"); // stage(kc+1) landed (mine)
        __builtin_amdgcn_sched_barrier(0);
        COMPUTE(p0);                                   // reads stage(kc), certified last phase
        __builtin_amdgcn_sched_barrier(0);
        __builtin_amdgcn_s_barrier();                  // all done reading buf kc; stage(kc+1) landed (all)
        char* tmp = p0; p0 = p1; p1 = p2; p2 = tmp;
    }
    asm volatile("s_waitcnt vmcnt(0)" ::: "memory");
    __builtin_amdgcn_s_barrier();
    __builtin_amdgcn_sched_barrier(0);
    #undef STAGE
    #undef COMPUTE

    // ---- epilogue: invg scale, softmax over r, dot with Q2 rows ----
    float* mred = (float*)smem;             // [4][160]
    float* mg   = (float*)(smem + 2560);    // [160]
    float* sred = (float*)(smem + 3200);    // [4][160]
    float* dred = (float*)(smem + 5760);    // [4][160]

    const float* sq = ssq32 + (size_t)b * NKC * RR;
    int c0 = wn * 64 + nl;
    float q0 = 0.f, q1 = 0.f;
    #pragma unroll
    for (int kc = 0; kc < NKC; ++kc) {
        q0 += sq[(size_t)kc * RR + c0];
        q1 += sq[(size_t)kc * RR + 32 + c0];
    }
    float iv0 = 1.f / fmaxf(sqrtf(q0), 1e-12f);
    float iv1 = 1.f / fmaxf(sqrtf(q1), 1e-12f);
    #pragma unroll
    for (int mt = 0; mt < 5; ++mt)
        #pragma unroll
        for (int gi = 0; gi < 16; ++gi) {
            acc[mt][0][gi] *= iv0;
            acc[mt][1][gi] *= iv1;
        }

    // pass 1: per-pair max over r
    #pragma unroll
    for (int mt = 0; mt < 5; ++mt) {
        #pragma unroll
        for (int e = 0; e < 8; ++e) {
            int g = 2 * e;
            float mx = fmaxf(acc[mt][0][g], acc[mt][1][g]);
            #pragma unroll
            for (int off = 1; off <= 16; off <<= 1)
                mx = fmaxf(mx, __shfl_xor(mx, off, 64));
            if (nl == 0) {
                int row = (g & 3) + 8 * (g >> 2) + 4 * kh;   // even
                mred[wn * 160 + wm * 80 + mt * 16 + (row >> 1)] = mx;
            }
        }
    }
    __syncthreads();
    if (tid < 160)
        mg[tid] = fmaxf(fmaxf(mred[tid], mred[160 + tid]),
                        fmaxf(mred[320 + tid], mred[480 + tid]));
    __syncthreads();

    // pass 2: exp-sum and weighted Q2 dot
    #pragma unroll
    for (int mt = 0; mt < 5; ++mt) {
        #pragma unroll
        for (int e = 0; e < 8; ++e) {
            int g = 2 * e;
            int row = (g & 3) + 8 * (g >> 2) + 4 * kh;
            int Pl = wm * 80 + mt * 16 + (row >> 1);
            float m = mg[Pl];
            float e0 = __expf(acc[mt][0][g] - m);
            float e1 = __expf(acc[mt][1][g] - m);
            float s = e0 + e1;
            float d = e0 * acc[mt][0][g + 1] + e1 * acc[mt][1][g + 1];
            #pragma unroll
            for (int off = 1; off <= 16; off <<= 1) {
                s += __shfl_xor(s, off, 64);
                d += __shfl_xor(d, off, 64);
            }
            if (nl == 0) {
                sred[wn * 160 + Pl] = s;
                dred[wn * 160 + Pl] = d;
            }
        }
    }
    __syncthreads();
    if (tid < 160) {
        float s = sred[tid] + sred[160 + tid] + sred[320 + tid] + sred[480 + tid];
        float d = dred[tid] + dred[160 + tid] + dred[320 + tid] + dred[480 + tid];
        int ig = t2h * 160 + tid;
        if (ig < NA) out[b * NA + ig] = d / s;
    }
}

// ---- launcher ----
extern "C" void kernel_launch(void* const* d_in, const int* in_sizes, int n_in,
                              void* d_out, int out_size, void* d_ws, size_t ws_size,
                              hipStream_t stream) {
    const float* img = (const float*)d_in[0];
    const float* V   = (const float*)d_in[1];
    const float* W1  = (const float*)d_in[2];
    const float* W2  = (const float*)d_in[3];
    float* out = (float*)d_out;

    char* ws = (char*)d_ws;
    size_t off = 0;
    float*    ssq32 = (float*)(ws + off);    off += (size_t)NB * NKC * RR * 4;
    _Float16* avT   = (_Float16*)(ws + off); off += (size_t)NB * CF * RR * 2;
    _Float16* Qb    = (_Float16*)(ws + off); off += (size_t)NKC * MT * 32 * 2;

    static bool attr_done = false;
    if (!attr_done) {
        hipFuncSetAttribute((const void*)k_gemm,
                            hipFuncAttributeMaxDynamicSharedMemorySize, 110592);
        attr_done = true;
    }

    k_prep<<<dim3(NB * NKC), 256, 0, stream>>>(img, ssq32, avT);
    k_q<<<dim3(NQ), 256, 0, stream>>>(V, W1, W2, Qb);
    k_gemm<<<dim3(256), 512, 110592, stream>>>(Qb, avT, ssq32, out);
}

// Round 5
// 264.308 us; speedup vs baseline: 1.1292x; 1.1292x over previous
//
#include <hip/hip_runtime.h>
#include <math.h>

#define NB   128
#define CF   1024
#define RR   256
#define NA   312
#define DV   300
#define MT   640
#define NKC  32
#define NQ   160
#define NPI  320          // padded i-pairs
#define ABYTES 40960      // A tile: 640 rows x 64 B
#define BBYTES 16384      // B tile: 32 f x 128 r x f32
#define BUFSZ  57344      // ABYTES + BBYTES

typedef _Float16 half8  __attribute__((ext_vector_type(8)));
typedef _Float16 half4  __attribute__((ext_vector_type(4)));
typedef float float16v  __attribute__((ext_vector_type(16)));
typedef float float4v   __attribute__((ext_vector_type(4)));

// async global->LDS, 16B/lane; dest = wave-uniform base + lane*16 (linear).
__device__ __forceinline__ void gll16(const void* g, void* l) {
    __builtin_amdgcn_global_load_lds(
        (const __attribute__((address_space(1))) void*)g,
        (__attribute__((address_space(3))) void*)l, 16, 0, 0);
}

// ---- K0: Q projection (pair-interleaved Qb rows: row 2i = Q1_i, 2i+1 = Q2_i) ----
__launch_bounds__(256, 4)
__global__ void k_q(const float* __restrict__ V, const float* __restrict__ W1,
                    const float* __restrict__ W2, _Float16* __restrict__ Qb) {
    int ib = blockIdx.x;
    int t  = threadIdx.x;
    bool isQ2 = ib >= 80;
    int i0l = (ib - (isQ2 ? 80 : 0)) * 4;
    __shared__ float inv4[4];
    float acc[4][4];
    #pragma unroll
    for (int ii = 0; ii < 4; ++ii)
        #pragma unroll
        for (int j = 0; j < 4; ++j) acc[ii][j] = 0.f;
    if (i0l < NA) {
        int row = t >> 6, l64 = t & 63;
        float s = 0.f;
        for (int v = l64; v < DV; v += 64) { float x = V[(i0l + row) * DV + v]; s += x * x; }
        #pragma unroll
        for (int o = 32; o; o >>= 1) s += __shfl_xor(s, o, 64);
        if (l64 == 0) inv4[row] = 1.f / fmaxf(sqrtf(s), 1e-12f);
        __syncthreads();
        const float* W  = isQ2 ? W2 : W1;
        const float* Vb = V + (size_t)i0l * DV;
        for (int v = 0; v < DV; v += 2) {
            float4v w0 = *(const float4v*)(W + (size_t)v * CF + t * 4);
            float4v w1 = *(const float4v*)(W + (size_t)(v + 1) * CF + t * 4);
            #pragma unroll
            for (int ii = 0; ii < 4; ++ii) {
                float a0 = Vb[(size_t)ii * DV + v];
                float a1 = Vb[(size_t)ii * DV + v + 1];
                #pragma unroll
                for (int j = 0; j < 4; ++j) acc[ii][j] += a0 * w0[j] + a1 * w1[j];
            }
        }
        #pragma unroll
        for (int ii = 0; ii < 4; ++ii)
            #pragma unroll
            for (int j = 0; j < 4; ++j) acc[ii][j] *= inv4[ii];
    }
    int fg = t >> 3;
    int fo = (t & 7) * 4;
    int q12 = isQ2 ? 1 : 0;
    #pragma unroll
    for (int ii = 0; ii < 4; ++ii) {
        half4 h;
        #pragma unroll
        for (int j = 0; j < 4; ++j) h[j] = (_Float16)acc[ii][j];
        *(half4*)&Qb[((size_t)fg * MT + (2 * (i0l + ii) + q12)) * 32 + fo] = h;
    }
}

// ---- K1: fused norm+transpose+GEMM+partial-softmax. block = (b, r-half). ----
// M=640 (pairs) x N=128 x K=1024. B built from raw f32 img in LDS (transposed
// read + cvt). Per-r sumsq accumulated in-loop; partial (m, sum, dot) emitted.
extern __shared__ char smem[];
__launch_bounds__(512, 2)
__global__ void k_fused(const float* __restrict__ img, const _Float16* __restrict__ Qb,
                        float* __restrict__ pm, float* __restrict__ ps,
                        float* __restrict__ pd) {
    int lin = blockIdx.x;          // 0..255
    int b   = lin >> 1;
    int rh  = lin & 1;

    int tid  = threadIdx.x;
    int lane = tid & 63;
    int w    = tid >> 6;           // 0..7
    int wm   = w >> 1;             // 0..3: rows [wm*160, +160)
    int wn   = w & 1;              // 0..1: cols [wn*64, +64)
    int nl   = lane & 31;
    int kh   = lane >> 5;

    // A: LDS slot s (16B) = kb*640+row; global chunk = (row*4+kb)*16. 5/thread.
    int aG[5];
    #pragma unroll
    for (int j = 0; j < 5; ++j) {
        int s = tid + j * 512;
        aG[j] = ((s % 640) * 4 + (s / 640)) * 16;
    }
    // B: LDS slot s = f*32 + r4 ([32f][128r] f32); global = f*1024 + r4*16. 2/thread.
    int bG[2];
    #pragma unroll
    for (int j = 0; j < 2; ++j) {
        int s = tid + j * 512;
        bG[j] = (s >> 5) * (RR * 4) + (s & 31) * 16;
    }
    const char* gA = (const char*)Qb;
    const char* gB = (const char*)img + ((size_t)b * CF * RR + (size_t)rh * 128) * 4;

    float16v acc[5][2];
    #pragma unroll
    for (int i = 0; i < 5; ++i)
        #pragma unroll
        for (int j = 0; j < 2; ++j)
            #pragma unroll
            for (int gi = 0; gi < 16; ++gi) acc[i][j][gi] = 0.f;
    float ssq = 0.f;

    #define STAGE(kc_) do {                                                        \
        int kcl = (kc_) < NKC ? (kc_) : (NKC - 1);                                 \
        char* buf = smem + (((kc_) & 1) ? BUFSZ : 0);                              \
        const char* aS = gA + (size_t)kcl * ABYTES;                                \
        const char* bS = gB + (size_t)kcl * 32768;                                 \
        _Pragma("unroll")                                                          \
        for (int j = 0; j < 5; ++j) gll16(aS + aG[j], buf + (tid + j * 512) * 16); \
        _Pragma("unroll")                                                          \
        for (int j = 0; j < 2; ++j)                                                \
            gll16(bS + bG[j], buf + ABYTES + (tid + j * 512) * 16);                \
    } while (0)

    #define COMPUTE(kc_) do {                                                      \
        char* buf = smem + (((kc_) & 1) ? BUFSZ : 0);                              \
        const char* Al = buf; const char* Bl = buf + ABYTES;                       \
        int c0 = wn * 64 + nl;                                                     \
        _Pragma("unroll")                                                          \
        for (int ks = 0; ks < 2; ++ks) {                                           \
            int kb = ks * 2 + kh;                                                  \
            float bv0[8], bv1[8];                                                  \
            _Pragma("unroll")                                                      \
            for (int j = 0; j < 8; ++j) {                                          \
                bv0[j] = *(const float*)(Bl + (((kb * 8 + j) * 128) + c0) * 4);    \
                bv1[j] = *(const float*)(Bl + (((kb * 8 + j) * 128) + c0 + 32) * 4); \
            }                                                                      \
            half8 bf0, bf1;                                                        \
            _Pragma("unroll")                                                      \
            for (int j = 0; j < 8; ++j) {                                          \
                bf0[j] = (_Float16)bv0[j]; bf1[j] = (_Float16)bv1[j];              \
            }                                                                      \
            _Pragma("unroll")                                                      \
            for (int mt = 0; mt < 5; ++mt) {                                       \
                half8 af = *(const half8*)(Al + ((size_t)kb * 640 + wm * 160 + mt * 32 + nl) * 16); \
                acc[mt][0] = __builtin_amdgcn_mfma_f32_32x32x16_f16(af, bf0, acc[mt][0], 0, 0, 0);  \
                acc[mt][1] = __builtin_amdgcn_mfma_f32_32x32x16_f16(af, bf1, acc[mt][1], 0, 0, 0);  \
            }                                                                      \
        }                                                                          \
    } while (0)

    STAGE(0);
    #pragma unroll 1
    for (int kc = 0; kc < NKC; ++kc) {
        STAGE(kc + 1);
        asm volatile("s_waitcnt vmcnt(7)" ::: "memory");   // stage(kc) landed (mine)
        __builtin_amdgcn_s_barrier();                      // stage(kc) landed (all)
        __builtin_amdgcn_sched_barrier(0);
        COMPUTE(kc);
        {   // per-r sumsq over this kc's 32 f (waves 0-1)
            if (tid < 128) {
                const char* Bl = smem + ((kc & 1) ? BUFSZ : 0) + ABYTES;
                #pragma unroll
                for (int f = 0; f < 32; ++f) {
                    float x = *(const float*)(Bl + (f * 128 + tid) * 4);
                    ssq += x * x;
                }
            }
        }
        __builtin_amdgcn_sched_barrier(0);
        __builtin_amdgcn_s_barrier();                      // all done reading buf kc
    }
    asm volatile("s_waitcnt vmcnt(0)" ::: "memory");       // drain tail dup-stage
    __builtin_amdgcn_s_barrier();
    __builtin_amdgcn_sched_barrier(0);
    #undef STAGE
    #undef COMPUTE

    // ---- epilogue (aliases buffer 0) ----
    float* ssq_lds = (float*)smem;              // [128]
    float* mred    = (float*)(smem + 512);      // [2][320]
    float* mg      = (float*)(smem + 3072);     // [320]
    float* sred    = (float*)(smem + 4352);     // [2][320]
    float* dred    = (float*)(smem + 6912);     // [2][320]

    if (tid < 128) ssq_lds[tid] = ssq;
    __syncthreads();
    int c0 = wn * 64 + nl;
    float iv0 = 1.f / fmaxf(sqrtf(ssq_lds[c0]), 1e-12f);
    float iv1 = 1.f / fmaxf(sqrtf(ssq_lds[c0 + 32]), 1e-12f);
    #pragma unroll
    for (int mt = 0; mt < 5; ++mt)
        #pragma unroll
        for (int gi = 0; gi < 16; ++gi) {
            acc[mt][0][gi] *= iv0;
            acc[mt][1][gi] *= iv1;
        }

    // pass 1: per-pair max over this half's 128 r
    #pragma unroll
    for (int mt = 0; mt < 5; ++mt) {
        #pragma unroll
        for (int e = 0; e < 8; ++e) {
            int g = 2 * e;
            float mx = fmaxf(acc[mt][0][g], acc[mt][1][g]);
            #pragma unroll
            for (int off = 1; off <= 16; off <<= 1)
                mx = fmaxf(mx, __shfl_xor(mx, off, 64));
            if (nl == 0) {
                int row = (g & 3) + 8 * (g >> 2) + 4 * kh;     // even, 0..30
                mred[wn * NPI + wm * 80 + mt * 16 + (row >> 1)] = mx;
            }
        }
    }
    __syncthreads();
    if (tid < NPI) mg[tid] = fmaxf(mred[tid], mred[NPI + tid]);
    __syncthreads();

    // pass 2: exp-sum and weighted Q2 dot (local max)
    #pragma unroll
    for (int mt = 0; mt < 5; ++mt) {
        #pragma unroll
        for (int e = 0; e < 8; ++e) {
            int g = 2 * e;
            int row = (g & 3) + 8 * (g >> 2) + 4 * kh;
            int i   = wm * 80 + mt * 16 + (row >> 1);
            float m  = mg[i];
            float e0 = __expf(acc[mt][0][g] - m);
            float e1 = __expf(acc[mt][1][g] - m);
            float s = e0 + e1;
            float d = e0 * acc[mt][0][g + 1] + e1 * acc[mt][1][g + 1];
            #pragma unroll
            for (int off = 1; off <= 16; off <<= 1) {
                s += __shfl_xor(s, off, 64);
                d += __shfl_xor(d, off, 64);
            }
            if (nl == 0) {
                sred[wn * NPI + i] = s;
                dred[wn * NPI + i] = d;
            }
        }
    }
    __syncthreads();
    if (tid < NPI) {
        size_t pb = ((size_t)b * 2 + rh) * NPI + tid;
        pm[pb] = mg[tid];
        ps[pb] = sred[tid] + sred[NPI + tid];
        pd[pb] = dred[tid] + dred[NPI + tid];
    }
}

// ---- K2: combine the two r-halves (flash-style) ----
__launch_bounds__(256, 4)
__global__ void k_comb(const float* __restrict__ pm, const float* __restrict__ ps,
                       const float* __restrict__ pd, float* __restrict__ out) {
    int idx = blockIdx.x * 256 + threadIdx.x;   // 0..40959 = 128*320
    int b = idx / NPI;
    int i = idx - b * NPI;
    float m0 = pm[(size_t)(b * 2) * NPI + i];
    float m1 = pm[(size_t)(b * 2 + 1) * NPI + i];
    float m  = fmaxf(m0, m1);
    float w0 = __expf(m0 - m), w1 = __expf(m1 - m);
    float s = ps[(size_t)(b * 2) * NPI + i] * w0 + ps[(size_t)(b * 2 + 1) * NPI + i] * w1;
    float d = pd[(size_t)(b * 2) * NPI + i] * w0 + pd[(size_t)(b * 2 + 1) * NPI + i] * w1;
    if (i < NA) out[(size_t)b * NA + i] = d / s;
}

// ---- launcher ----
extern "C" void kernel_launch(void* const* d_in, const int* in_sizes, int n_in,
                              void* d_out, int out_size, void* d_ws, size_t ws_size,
                              hipStream_t stream) {
    const float* img = (const float*)d_in[0];
    const float* V   = (const float*)d_in[1];
    const float* W1  = (const float*)d_in[2];
    const float* W2  = (const float*)d_in[3];
    float* out = (float*)d_out;

    char* ws = (char*)d_ws;
    size_t off = 0;
    _Float16* Qb = (_Float16*)(ws + off); off += (size_t)NKC * MT * 32 * 2;
    float*    pm = (float*)(ws + off);    off += (size_t)NB * 2 * NPI * 4;
    float*    ps = (float*)(ws + off);    off += (size_t)NB * 2 * NPI * 4;
    float*    pd = (float*)(ws + off);    off += (size_t)NB * 2 * NPI * 4;

    static bool attr_done = false;
    if (!attr_done) {
        hipFuncSetAttribute((const void*)k_fused,
                            hipFuncAttributeMaxDynamicSharedMemorySize, 2 * BUFSZ);
        attr_done = true;
    }

    k_q<<<dim3(NQ), 256, 0, stream>>>(V, W1, W2, Qb);
    k_fused<<<dim3(256), 512, 2 * BUFSZ, stream>>>(img, Qb, pm, ps, pd);
    k_comb<<<dim3(160), 256, 0, stream>>>(pm, ps, pd, out);
}